// Round 1
// 318.478 us; speedup vs baseline: 1.0231x; 1.0231x over previous
//
#include <hip/hip_runtime.h>

#define NN 50000
#define EE 800000
#define FIN 256
#define F1 128
#define F2 40
#define CAP 48     // bucket capacity per node, real edges only (deg~Poisson(16))
#define G1B ((NN + 127) / 128)            // 391 gemm blocks
#define FILLB ((EE + 255) / 256)          // 3125 fill blocks (1 edge/thread)
#define PB ((NN + 63) / 64)               // 782 blocks per gather1 phase

typedef unsigned int u32;
typedef unsigned short u16;

// fp32 -> bf16 (RNE), returned in low 16 bits
static __device__ __forceinline__ u32 f2bf(float f) {
  u32 u = __float_as_uint(f);
  return (u + 0x7FFFu + ((u >> 16) & 1u)) >> 16;
}
#define BF_LO(u) __uint_as_float((u) << 16)
#define BF_HI(u) __uint_as_float((u) & 0xFFFF0000u)

// ---- fused: GEMM1(128x128 tile)+attention dots  ||  bucketed fill (real edges) ----
// h1bf layout is SoA-by-phase: [phase][node][16 u32]  (each phase table = 3.2 MB,
// fits one XCD's 4 MB L2 -- gather1 pins phase p to XCD pair {2p,2p+1})
__global__ __launch_bounds__(256) void g1f_kernel(const float* __restrict__ x,
                                                  const float* __restrict__ W1,
                                                  const float* __restrict__ att_src,
                                                  const float* __restrict__ att_dst,
                                                  u32* __restrict__ h1bf,
                                                  float* __restrict__ a_src,
                                                  float* __restrict__ a_dst,
                                                  const int* __restrict__ ei,
                                                  int* __restrict__ cnt,
                                                  int* __restrict__ csr) {
  __shared__ float Alds[16 * 132];
  __shared__ float Blds[16 * 128];
  __shared__ float att_s[128], att_d[128];
  const int t = threadIdx.x;

  if (blockIdx.x >= G1B) {
    // ------- fill path: one real edge per thread, no self-loops -------
    int e = (blockIdx.x - G1B) * 256 + t;
    if (e < EE) {
      int src = ei[e];
      int dst = ei[EE + e];
      int p = atomicAdd(cnt + dst, 1);
      if (p < CAP) csr[dst * CAP + p] = src;
    }
    return;
  }

  // ---------------- GEMM path ----------------
  if (t < 128) { att_s[t] = att_src[t]; att_d[t] = att_dst[t]; }
  const int m0 = blockIdx.x * 128;
  const int arow = t >> 1;
  const int akk = (t & 1) * 8;
  const int brow = t >> 4;
  const int bc = (t & 15) * 8;
  const int ty = t >> 4;
  const int tx = t & 15;

  float acc[8][8];
#pragma unroll
  for (int i = 0; i < 8; ++i)
#pragma unroll
    for (int j = 0; j < 8; ++j) acc[i][j] = 0.f;

  for (int k0 = 0; k0 < FIN; k0 += 16) {
    float4 a0 = {0.f, 0.f, 0.f, 0.f}, a1 = {0.f, 0.f, 0.f, 0.f};
    int gr = m0 + arow;
    if (gr < NN) {
      a0 = *(const float4*)(x + (size_t)gr * FIN + k0 + akk);
      a1 = *(const float4*)(x + (size_t)gr * FIN + k0 + akk + 4);
    }
    float4 b0 = *(const float4*)(W1 + (size_t)(k0 + brow) * F1 + bc);
    float4 b1 = *(const float4*)(W1 + (size_t)(k0 + brow) * F1 + bc + 4);
    __syncthreads();
    Alds[(akk + 0) * 132 + arow] = a0.x;
    Alds[(akk + 1) * 132 + arow] = a0.y;
    Alds[(akk + 2) * 132 + arow] = a0.z;
    Alds[(akk + 3) * 132 + arow] = a0.w;
    Alds[(akk + 4) * 132 + arow] = a1.x;
    Alds[(akk + 5) * 132 + arow] = a1.y;
    Alds[(akk + 6) * 132 + arow] = a1.z;
    Alds[(akk + 7) * 132 + arow] = a1.w;
    *(float4*)(Blds + brow * 128 + bc) = b0;
    *(float4*)(Blds + brow * 128 + bc + 4) = b1;
    __syncthreads();
#pragma unroll
    for (int k = 0; k < 16; ++k) {
      float4 av0 = *(const float4*)(Alds + k * 132 + ty * 8);
      float4 av1 = *(const float4*)(Alds + k * 132 + ty * 8 + 4);
      float4 bv0 = *(const float4*)(Blds + k * 128 + tx * 8);
      float4 bv1 = *(const float4*)(Blds + k * 128 + tx * 8 + 4);
      float aa[8] = {av0.x, av0.y, av0.z, av0.w, av1.x, av1.y, av1.z, av1.w};
      float bb[8] = {bv0.x, bv0.y, bv0.z, bv0.w, bv1.x, bv1.y, bv1.z, bv1.w};
#pragma unroll
      for (int i = 0; i < 8; ++i)
#pragma unroll
        for (int j = 0; j < 8; ++j) acc[i][j] = fmaf(aa[i], bb[j], acc[i][j]);
    }
  }
#pragma unroll
  for (int i = 0; i < 8; ++i) {
    int gr = m0 + ty * 8 + i;
    if (gr < NN) {
      uint4 w;
      w.x = f2bf(acc[i][0]) | (f2bf(acc[i][1]) << 16);
      w.y = f2bf(acc[i][2]) | (f2bf(acc[i][3]) << 16);
      w.z = f2bf(acc[i][4]) | (f2bf(acc[i][5]) << 16);
      w.w = f2bf(acc[i][6]) | (f2bf(acc[i][7]) << 16);
      // SoA-by-phase: phase = tx>>2 (cols tx*8.. are within head tx>>2),
      // offset within 16-u32 phase row = (tx&3)*4
      *(uint4*)(h1bf + ((size_t)(tx >> 2) * NN + gr) * 16 + (tx & 3) * 4) = w;
    }
  }
#pragma unroll
  for (int i = 0; i < 8; ++i) {
    float ps = 0.f, pd = 0.f;
#pragma unroll
    for (int j = 0; j < 8; ++j) {
      int c = tx * 8 + j;
      ps += acc[i][j] * att_s[c];
      pd += acc[i][j] * att_d[c];
    }
    ps += __shfl_xor(ps, 1); pd += __shfl_xor(pd, 1);
    ps += __shfl_xor(ps, 2); pd += __shfl_xor(pd, 2);
    if ((tx & 3) == 0) {
      int gr = m0 + ty * 8 + i;
      if (gr < NN) {
        int head = tx >> 2;
        a_src[gr * 4 + head] = ps;
        a_dst[gr * 4 + head] = pd;
      }
    }
  }
}

// ---- gather layer1, head-phased with phase->XCD affinity, analytic self-loop ----
// dispatch index d -> xcd = d&7 (HW round-robin), phase p = xcd>>1,
// node-block nb = (d>>3)*2 + (xcd&1).  Phase p's 3.2 MB h1bf table is then
// only touched by XCD pair {2p,2p+1}, each of whose 4 MB L2 holds it fully.
__global__ __launch_bounds__(256) void gather1_kernel(const int* __restrict__ cnt,
                                                      const int* __restrict__ csr,
                                                      const float* __restrict__ a_src,
                                                      const float* __restrict__ a_dst,
                                                      const u32* __restrict__ h1bf,
                                                      const float* __restrict__ b1,
                                                      float* __restrict__ h1b,
                                                      float* __restrict__ bnsum,
                                                      float* __restrict__ bnsq) {
  __shared__ float bns[32], bnq[32];
  int t = threadIdx.x;
  if (t < 32) { bns[t] = 0.f; bnq[t] = 0.f; }
  __syncthreads();
  int d = blockIdx.x;
  int xcd = d & 7;
  int p = xcd >> 1;                     // head / column phase, pinned to XCD pair
  int nb = ((d >> 3) << 1) + (xcd & 1); // 0..781 (PB=782, even)
  int n = nb * 64 + (t >> 2);
  int l = t & 3;
  int f0 = p * 32 + l * 8;
  if (n < NN) {
    float adst = a_dst[n * 4 + p];
    float acc[8] = {0.f, 0.f, 0.f, 0.f, 0.f, 0.f, 0.f, 0.f};
    float ssum = 0.f;
    const u32* hb = h1bf + (size_t)p * NN * 16 + l * 4;   // SoA phase table
    // analytic self-loop: own row, coalesced across the block
    {
      float e0 = a_src[n * 4 + p] + adst;
      e0 = e0 > 0.f ? e0 : 0.2f * e0;
      float x0 = __expf(e0);
      uint4 q = *(const uint4*)(hb + (size_t)n * 16);
      acc[0] = fmaf(x0, BF_LO(q.x), acc[0]); acc[1] = fmaf(x0, BF_HI(q.x), acc[1]);
      acc[2] = fmaf(x0, BF_LO(q.y), acc[2]); acc[3] = fmaf(x0, BF_HI(q.y), acc[3]);
      acc[4] = fmaf(x0, BF_LO(q.z), acc[4]); acc[5] = fmaf(x0, BF_HI(q.z), acc[5]);
      acc[6] = fmaf(x0, BF_LO(q.w), acc[6]); acc[7] = fmaf(x0, BF_HI(q.w), acc[7]);
      ssum += x0;
    }
    const int* row = csr + n * CAP;
    int m = cnt[n]; if (m > CAP) m = CAP;
    int i = 0;
    for (; i + 3 < m; i += 4) {
      int4 s4 = *(const int4*)(row + i);
      float e0 = a_src[s4.x * 4 + p] + adst;
      float e1 = a_src[s4.y * 4 + p] + adst;
      float e2 = a_src[s4.z * 4 + p] + adst;
      float e3 = a_src[s4.w * 4 + p] + adst;
      uint4 q0 = *(const uint4*)(hb + (size_t)s4.x * 16);
      uint4 q1 = *(const uint4*)(hb + (size_t)s4.y * 16);
      uint4 q2 = *(const uint4*)(hb + (size_t)s4.z * 16);
      uint4 q3 = *(const uint4*)(hb + (size_t)s4.w * 16);
      e0 = e0 > 0.f ? e0 : 0.2f * e0;  float x0 = __expf(e0);
      e1 = e1 > 0.f ? e1 : 0.2f * e1;  float x1 = __expf(e1);
      e2 = e2 > 0.f ? e2 : 0.2f * e2;  float x2 = __expf(e2);
      e3 = e3 > 0.f ? e3 : 0.2f * e3;  float x3 = __expf(e3);
      acc[0] = fmaf(x0, BF_LO(q0.x), acc[0]); acc[1] = fmaf(x0, BF_HI(q0.x), acc[1]);
      acc[2] = fmaf(x0, BF_LO(q0.y), acc[2]); acc[3] = fmaf(x0, BF_HI(q0.y), acc[3]);
      acc[4] = fmaf(x0, BF_LO(q0.z), acc[4]); acc[5] = fmaf(x0, BF_HI(q0.z), acc[5]);
      acc[6] = fmaf(x0, BF_LO(q0.w), acc[6]); acc[7] = fmaf(x0, BF_HI(q0.w), acc[7]);
      acc[0] = fmaf(x1, BF_LO(q1.x), acc[0]); acc[1] = fmaf(x1, BF_HI(q1.x), acc[1]);
      acc[2] = fmaf(x1, BF_LO(q1.y), acc[2]); acc[3] = fmaf(x1, BF_HI(q1.y), acc[3]);
      acc[4] = fmaf(x1, BF_LO(q1.z), acc[4]); acc[5] = fmaf(x1, BF_HI(q1.z), acc[5]);
      acc[6] = fmaf(x1, BF_LO(q1.w), acc[6]); acc[7] = fmaf(x1, BF_HI(q1.w), acc[7]);
      acc[0] = fmaf(x2, BF_LO(q2.x), acc[0]); acc[1] = fmaf(x2, BF_HI(q2.x), acc[1]);
      acc[2] = fmaf(x2, BF_LO(q2.y), acc[2]); acc[3] = fmaf(x2, BF_HI(q2.y), acc[3]);
      acc[4] = fmaf(x2, BF_LO(q2.z), acc[4]); acc[5] = fmaf(x2, BF_HI(q2.z), acc[5]);
      acc[6] = fmaf(x2, BF_LO(q2.w), acc[6]); acc[7] = fmaf(x2, BF_HI(q2.w), acc[7]);
      acc[0] = fmaf(x3, BF_LO(q3.x), acc[0]); acc[1] = fmaf(x3, BF_HI(q3.x), acc[1]);
      acc[2] = fmaf(x3, BF_LO(q3.y), acc[2]); acc[3] = fmaf(x3, BF_HI(q3.y), acc[3]);
      acc[4] = fmaf(x3, BF_LO(q3.z), acc[4]); acc[5] = fmaf(x3, BF_HI(q3.z), acc[5]);
      acc[6] = fmaf(x3, BF_LO(q3.w), acc[6]); acc[7] = fmaf(x3, BF_HI(q3.w), acc[7]);
      ssum += x0 + x1 + x2 + x3;
    }
    for (; i < m; ++i) {
      int s0 = row[i];
      float e0 = a_src[s0 * 4 + p] + adst;
      e0 = e0 > 0.f ? e0 : 0.2f * e0;
      float x0 = __expf(e0);
      uint4 q = *(const uint4*)(hb + (size_t)s0 * 16);
      acc[0] = fmaf(x0, BF_LO(q.x), acc[0]); acc[1] = fmaf(x0, BF_HI(q.x), acc[1]);
      acc[2] = fmaf(x0, BF_LO(q.y), acc[2]); acc[3] = fmaf(x0, BF_HI(q.y), acc[3]);
      acc[4] = fmaf(x0, BF_LO(q.z), acc[4]); acc[5] = fmaf(x0, BF_HI(q.z), acc[5]);
      acc[6] = fmaf(x0, BF_LO(q.w), acc[6]); acc[7] = fmaf(x0, BF_HI(q.w), acc[7]);
      ssum += x0;
    }
    float inv = 1.f / (ssum + 1e-16f);
    float4 b0 = *(const float4*)(b1 + f0);
    float4 b4 = *(const float4*)(b1 + f0 + 4);
    float o[8];
    o[0] = acc[0] * inv + b0.x; o[1] = acc[1] * inv + b0.y;
    o[2] = acc[2] * inv + b0.z; o[3] = acc[3] * inv + b0.w;
    o[4] = acc[4] * inv + b4.x; o[5] = acc[5] * inv + b4.y;
    o[6] = acc[6] * inv + b4.z; o[7] = acc[7] * inv + b4.w;
    float4 w0 = {o[0], o[1], o[2], o[3]};
    float4 w1 = {o[4], o[5], o[6], o[7]};
    *(float4*)(h1b + (size_t)n * F1 + f0) = w0;
    *(float4*)(h1b + (size_t)n * F1 + f0 + 4) = w1;
    int lb = l * 8;
#pragma unroll
    for (int j = 0; j < 8; ++j) {
      atomicAdd(&bns[lb + j], o[j]);
      atomicAdd(&bnq[lb + j], o[j] * o[j]);
    }
  }
  __syncthreads();
  if (t < 32) {
    atomicAdd(bnsum + p * 32 + t, bns[t]);
    atomicAdd(bnsq + p * 32 + t, bnq[t]);
  }
}

// -- GEMM2 (BN stats + BN+ELU fused, a2 dots fused): h2 split A[64B]/B[16B] --
__global__ __launch_bounds__(256) void gemm2_kernel(const float* __restrict__ hpre,
                                                    const float* __restrict__ W2,
                                                    const float* __restrict__ bnsum,
                                                    const float* __restrict__ bnsq,
                                                    const float* __restrict__ gamma,
                                                    const float* __restrict__ beta,
                                                    u16* __restrict__ h2a,
                                                    u16* __restrict__ h2b,
                                                    const float* __restrict__ att_src2,
                                                    const float* __restrict__ att_dst2,
                                                    float* __restrict__ a_src2,
                                                    float* __restrict__ a_dst2) {
  __shared__ float Wlds[128 * 40];
  __shared__ float Alds[16 * 128];
  __shared__ float sc[128], sh[128];
  int t = threadIdx.x;
  for (int i = t; i < 128 * 40; i += 256) Wlds[i] = W2[i];
  if (t < 128) {
    const float invN = 1.f / (float)NN;
    float mu = bnsum[t] * invN;
    float var = bnsq[t] * invN - mu * mu;
    float s = gamma[t] * rsqrtf(var + 1e-5f);
    sc[t] = s;
    sh[t] = beta[t] - mu * s;
  }
  int tr = t >> 3;
  int tc = t & 7;
  float as5[5], ad5[5];
#pragma unroll
  for (int j = 0; j < 5; ++j) { as5[j] = att_src2[tc * 5 + j]; ad5[j] = att_dst2[tc * 5 + j]; }
  int n0 = blockIdx.x * 128;
  int lrow = t >> 1;
  int lkk = (t & 1) * 8;
  float acc[4][5];
#pragma unroll
  for (int i = 0; i < 4; ++i)
#pragma unroll
    for (int j = 0; j < 5; ++j) acc[i][j] = 0.f;

  for (int k0 = 0; k0 < F1; k0 += 16) {
    float av[8];
    int gn = n0 + lrow;
    if (gn < NN) {
      float4 v0 = *(const float4*)(hpre + (size_t)gn * F1 + k0 + lkk);
      float4 v1 = *(const float4*)(hpre + (size_t)gn * F1 + k0 + lkk + 4);
      av[0] = v0.x; av[1] = v0.y; av[2] = v0.z; av[3] = v0.w;
      av[4] = v1.x; av[5] = v1.y; av[6] = v1.z; av[7] = v1.w;
    } else {
#pragma unroll
      for (int j = 0; j < 8; ++j) av[j] = 0.f;
    }
    __syncthreads();
#pragma unroll
    for (int j = 0; j < 8; ++j) {
      int kg = k0 + lkk + j;
      float a = av[j] * sc[kg] + sh[kg];
      a = a > 0.f ? a : (__expf(a) - 1.f);
      Alds[(lkk + j) * 128 + lrow] = a;
    }
    __syncthreads();
#pragma unroll
    for (int k = 0; k < 16; ++k) {
      float4 a4 = *(const float4*)(Alds + k * 128 + tr * 4);
      float aa[4] = {a4.x, a4.y, a4.z, a4.w};
      float w[5];
#pragma unroll
      for (int j = 0; j < 5; ++j) w[j] = Wlds[(k0 + k) * 40 + tc * 5 + j];
#pragma unroll
      for (int i = 0; i < 4; ++i)
#pragma unroll
        for (int j = 0; j < 5; ++j) acc[i][j] = fmaf(aa[i], w[j], acc[i][j]);
    }
  }
#pragma unroll
  for (int i = 0; i < 4; ++i) {
    int gn = n0 + tr * 4 + i;
    if (gn < NN) {
#pragma unroll
      for (int j = 0; j < 5; ++j) {
        int f = tc * 5 + j;
        u16 v = (u16)f2bf(acc[i][j]);
        if (f < 32) h2a[(size_t)gn * 32 + f] = v;
        else        h2b[(size_t)gn * 8 + (f - 32)] = v;
      }
    }
  }
#pragma unroll
  for (int i = 0; i < 4; ++i) {
    float ps = 0.f, pd = 0.f;
#pragma unroll
    for (int j = 0; j < 5; ++j) { ps += acc[i][j] * as5[j]; pd += acc[i][j] * ad5[j]; }
#pragma unroll
    for (int off = 1; off < 8; off <<= 1) {
      ps += __shfl_xor(ps, off);
      pd += __shfl_xor(pd, off);
    }
    if (tc == 0) {
      int gn = n0 + tr * 4 + i;
      if (gn < NN) { a_src2[gn] = ps; a_dst2[gn] = pd; }
    }
  }
}

// ---- gather layer2: split tables, analytic self-loop; writes output ----
// 8 lanes/node: l=0..3 load A (64B aligned row, lanes share line), l=4 loads B.
__global__ __launch_bounds__(256) void gather2_kernel(const int* __restrict__ cnt,
                                                      const int* __restrict__ csr,
                                                      const float* __restrict__ a_src,
                                                      const float* __restrict__ a_dst,
                                                      const u32* __restrict__ h2a,
                                                      const u32* __restrict__ h2b,
                                                      const float* __restrict__ b2,
                                                      float* __restrict__ out) {
  int t = threadIdx.x;
  int n = blockIdx.x * 32 + (t >> 3);
  if (n >= NN) return;
  int l = t & 7;
  bool act = (l < 5);
  bool isA = (l < 4);
  float adst = a_dst[n];
  float acc[8] = {0.f, 0.f, 0.f, 0.f, 0.f, 0.f, 0.f, 0.f};
  float ssum = 0.f;
  const uint4 zz = {0u, 0u, 0u, 0u};
  // analytic self-loop (own row, coalesced)
  {
    float e0 = a_src[n] + adst;
    e0 = e0 > 0.f ? e0 : 0.2f * e0;
    float x0 = __expf(e0);
    uint4 q = act ? (isA ? *(const uint4*)(h2a + (size_t)n * 16 + l * 4)
                         : *(const uint4*)(h2b + (size_t)n * 4)) : zz;
    acc[0] = fmaf(x0, BF_LO(q.x), acc[0]); acc[1] = fmaf(x0, BF_HI(q.x), acc[1]);
    acc[2] = fmaf(x0, BF_LO(q.y), acc[2]); acc[3] = fmaf(x0, BF_HI(q.y), acc[3]);
    acc[4] = fmaf(x0, BF_LO(q.z), acc[4]); acc[5] = fmaf(x0, BF_HI(q.z), acc[5]);
    acc[6] = fmaf(x0, BF_LO(q.w), acc[6]); acc[7] = fmaf(x0, BF_HI(q.w), acc[7]);
    ssum += x0;
  }
  const int* row = csr + n * CAP;
  int m = cnt[n]; if (m > CAP) m = CAP;
  int i = 0;
  for (; i + 3 < m; i += 4) {
    int4 s4 = *(const int4*)(row + i);
    float e0 = a_src[s4.x] + adst;
    float e1 = a_src[s4.y] + adst;
    float e2 = a_src[s4.z] + adst;
    float e3 = a_src[s4.w] + adst;
    uint4 q0 = act ? (isA ? *(const uint4*)(h2a + (size_t)s4.x * 16 + l * 4)
                          : *(const uint4*)(h2b + (size_t)s4.x * 4)) : zz;
    uint4 q1 = act ? (isA ? *(const uint4*)(h2a + (size_t)s4.y * 16 + l * 4)
                          : *(const uint4*)(h2b + (size_t)s4.y * 4)) : zz;
    uint4 q2 = act ? (isA ? *(const uint4*)(h2a + (size_t)s4.z * 16 + l * 4)
                          : *(const uint4*)(h2b + (size_t)s4.z * 4)) : zz;
    uint4 q3 = act ? (isA ? *(const uint4*)(h2a + (size_t)s4.w * 16 + l * 4)
                          : *(const uint4*)(h2b + (size_t)s4.w * 4)) : zz;
    e0 = e0 > 0.f ? e0 : 0.2f * e0;  float x0 = __expf(e0);
    e1 = e1 > 0.f ? e1 : 0.2f * e1;  float x1 = __expf(e1);
    e2 = e2 > 0.f ? e2 : 0.2f * e2;  float x2 = __expf(e2);
    e3 = e3 > 0.f ? e3 : 0.2f * e3;  float x3 = __expf(e3);
    acc[0] = fmaf(x0, BF_LO(q0.x), acc[0]); acc[1] = fmaf(x0, BF_HI(q0.x), acc[1]);
    acc[2] = fmaf(x0, BF_LO(q0.y), acc[2]); acc[3] = fmaf(x0, BF_HI(q0.y), acc[3]);
    acc[4] = fmaf(x0, BF_LO(q0.z), acc[4]); acc[5] = fmaf(x0, BF_HI(q0.z), acc[5]);
    acc[6] = fmaf(x0, BF_LO(q0.w), acc[6]); acc[7] = fmaf(x0, BF_HI(q0.w), acc[7]);
    acc[0] = fmaf(x1, BF_LO(q1.x), acc[0]); acc[1] = fmaf(x1, BF_HI(q1.x), acc[1]);
    acc[2] = fmaf(x1, BF_LO(q1.y), acc[2]); acc[3] = fmaf(x1, BF_HI(q1.y), acc[3]);
    acc[4] = fmaf(x1, BF_LO(q1.z), acc[4]); acc[5] = fmaf(x1, BF_HI(q1.z), acc[5]);
    acc[6] = fmaf(x1, BF_LO(q1.w), acc[6]); acc[7] = fmaf(x1, BF_HI(q1.w), acc[7]);
    acc[0] = fmaf(x2, BF_LO(q2.x), acc[0]); acc[1] = fmaf(x2, BF_HI(q2.x), acc[1]);
    acc[2] = fmaf(x2, BF_LO(q2.y), acc[2]); acc[3] = fmaf(x2, BF_HI(q2.y), acc[3]);
    acc[4] = fmaf(x2, BF_LO(q2.z), acc[4]); acc[5] = fmaf(x2, BF_HI(q2.z), acc[5]);
    acc[6] = fmaf(x2, BF_LO(q2.w), acc[6]); acc[7] = fmaf(x2, BF_HI(q2.w), acc[7]);
    acc[0] = fmaf(x3, BF_LO(q3.x), acc[0]); acc[1] = fmaf(x3, BF_HI(q3.x), acc[1]);
    acc[2] = fmaf(x3, BF_LO(q3.y), acc[2]); acc[3] = fmaf(x3, BF_HI(q3.y), acc[3]);
    acc[4] = fmaf(x3, BF_LO(q3.z), acc[4]); acc[5] = fmaf(x3, BF_HI(q3.z), acc[5]);
    acc[6] = fmaf(x3, BF_LO(q3.w), acc[6]); acc[7] = fmaf(x3, BF_HI(q3.w), acc[7]);
    ssum += x0 + x1 + x2 + x3;
  }
  for (; i < m; ++i) {
    int s0 = row[i];
    float e0 = a_src[s0] + adst;
    e0 = e0 > 0.f ? e0 : 0.2f * e0;
    float x0 = __expf(e0);
    uint4 q = act ? (isA ? *(const uint4*)(h2a + (size_t)s0 * 16 + l * 4)
                         : *(const uint4*)(h2b + (size_t)s0 * 4)) : zz;
    acc[0] = fmaf(x0, BF_LO(q.x), acc[0]); acc[1] = fmaf(x0, BF_HI(q.x), acc[1]);
    acc[2] = fmaf(x0, BF_LO(q.y), acc[2]); acc[3] = fmaf(x0, BF_HI(q.y), acc[3]);
    acc[4] = fmaf(x0, BF_LO(q.z), acc[4]); acc[5] = fmaf(x0, BF_HI(q.z), acc[5]);
    acc[6] = fmaf(x0, BF_LO(q.w), acc[6]); acc[7] = fmaf(x0, BF_HI(q.w), acc[7]);
    ssum += x0;
  }
  float inv = 1.f / (ssum + 1e-16f);
  if (act) {
    float* op = out + (size_t)n * F2 + l * 8;
#pragma unroll
    for (int j = 0; j < 8; ++j) op[j] = acc[j] * inv + b2[l * 8 + j];
  }
}

extern "C" void kernel_launch(void* const* d_in, const int* in_sizes, int n_in,
                              void* d_out, int out_size, void* d_ws, size_t ws_size,
                              hipStream_t stream) {
  const float* x        = (const float*)d_in[0];
  const int*   ei       = (const int*)d_in[1];
  const float* W1       = (const float*)d_in[2];
  const float* att_src1 = (const float*)d_in[3];
  const float* att_dst1 = (const float*)d_in[4];
  const float* b1       = (const float*)d_in[5];
  const float* gamma    = (const float*)d_in[6];
  const float* beta     = (const float*)d_in[7];
  const float* W2       = (const float*)d_in[8];
  const float* att_src2 = (const float*)d_in[9];
  const float* att_dst2 = (const float*)d_in[10];
  const float* b2       = (const float*)d_in[11];
  float* out = (float*)d_out;

  // ---- workspace layout (16B-aligned chunks) ----
  int* cnt      = (int*)d_ws;                  // 50048 (zeroed)
  float* bnsum  = (float*)(cnt + 50048);       // 128   (zeroed)
  float* bnsq   = bnsum + 128;                 // 128   (zeroed)
  int* csr      = (int*)(bnsq + 128);          // 50000*48 = 2,400,000
  u32* h1bf     = (u32*)(csr + NN * CAP);      // 3,200,000 (4 phases * 50000*16)
  float* h1b    = (float*)(h1bf + 3200000);    // 6,400,000
  u32* h2a      = (u32*)(h1b + 6400000);       // 800,000 (50000*16, 64B rows)
  u32* h2b      = h2a + 800000;                // 200,000 (50000*4, 16B rows)
  float* a_src1 = (float*)(h2b + 200000);      // 200000
  float* a_dst1 = a_src1 + 200000;             // 200000
  float* a_src2 = a_dst1 + 200000;             // 50000
  float* a_dst2 = a_src2 + 50000;              // 50000

  hipMemsetAsync(cnt, 0, (50048 + 256) * sizeof(int), stream);

  g1f_kernel<<<G1B + FILLB, 256, 0, stream>>>(x, W1, att_src1, att_dst1,
                                              h1bf, a_src1, a_dst1,
                                              ei, cnt, csr);
  gather1_kernel<<<4 * PB, 256, 0, stream>>>(cnt, csr, a_src1, a_dst1,
                                             h1bf, b1, h1b, bnsum, bnsq);
  gemm2_kernel<<<(NN + 127) / 128, 256, 0, stream>>>(h1b, W2, bnsum, bnsq,
                                                     gamma, beta,
                                                     (u16*)h2a, (u16*)h2b,
                                                     att_src2, att_dst2,
                                                     a_src2, a_dst2);
  gather2_kernel<<<(NN + 31) / 32, 256, 0, stream>>>(cnt, csr, a_src2, a_dst2,
                                                     h2a, h2b, b2, out);
}

// Round 2
// 313.062 us; speedup vs baseline: 1.0408x; 1.0173x over previous
//
#include <hip/hip_runtime.h>

#define NN 50000
#define EE 800000
#define FIN 256
#define F1 128
#define F2 40
#define CAP 48     // bucket capacity per node, real edges only (deg~Poisson(16))
#define G1B ((NN + 127) / 128)            // 391 gemm blocks
#define FILLB ((EE + 255) / 256)          // 3125 fill blocks (1 edge/thread)
#define G1PB 3126                          // gather1: node-blocks per phase (16 nodes/blk, padded even)
#define G2B ((NN + 15) / 16)               // gather2: 3125 blocks (16 nodes/blk)

typedef unsigned int u32;
typedef unsigned short u16;

// fp32 -> bf16 (RNE), returned in low 16 bits
static __device__ __forceinline__ u32 f2bf(float f) {
  u32 u = __float_as_uint(f);
  return (u + 0x7FFFu + ((u >> 16) & 1u)) >> 16;
}
#define BF_LO(u) __uint_as_float((u) << 16)
#define BF_HI(u) __uint_as_float((u) & 0xFFFF0000u)

// ---- fused: GEMM1(128x128 tile)+attention dots  ||  bucketed fill (real edges) ----
// h1bf layout is SoA-by-phase: [phase][node][16 u32]  (each phase table = 3.2 MB,
// fits one XCD's 4 MB L2 -- gather1 pins phase p to XCD pair {2p,2p+1})
__global__ __launch_bounds__(256) void g1f_kernel(const float* __restrict__ x,
                                                  const float* __restrict__ W1,
                                                  const float* __restrict__ att_src,
                                                  const float* __restrict__ att_dst,
                                                  u32* __restrict__ h1bf,
                                                  float* __restrict__ a_src,
                                                  float* __restrict__ a_dst,
                                                  const int* __restrict__ ei,
                                                  int* __restrict__ cnt,
                                                  int* __restrict__ csr) {
  __shared__ float Alds[16 * 132];
  __shared__ float Blds[16 * 128];
  __shared__ float att_s[128], att_d[128];
  const int t = threadIdx.x;

  if (blockIdx.x >= G1B) {
    // ------- fill path: one real edge per thread, no self-loops -------
    int e = (blockIdx.x - G1B) * 256 + t;
    if (e < EE) {
      int src = ei[e];
      int dst = ei[EE + e];
      int p = atomicAdd(cnt + dst, 1);
      if (p < CAP) csr[dst * CAP + p] = src;
    }
    return;
  }

  // ---------------- GEMM path ----------------
  if (t < 128) { att_s[t] = att_src[t]; att_d[t] = att_dst[t]; }
  const int m0 = blockIdx.x * 128;
  const int arow = t >> 1;
  const int akk = (t & 1) * 8;
  const int brow = t >> 4;
  const int bc = (t & 15) * 8;
  const int ty = t >> 4;
  const int tx = t & 15;

  float acc[8][8];
#pragma unroll
  for (int i = 0; i < 8; ++i)
#pragma unroll
    for (int j = 0; j < 8; ++j) acc[i][j] = 0.f;

  for (int k0 = 0; k0 < FIN; k0 += 16) {
    float4 a0 = {0.f, 0.f, 0.f, 0.f}, a1 = {0.f, 0.f, 0.f, 0.f};
    int gr = m0 + arow;
    if (gr < NN) {
      a0 = *(const float4*)(x + (size_t)gr * FIN + k0 + akk);
      a1 = *(const float4*)(x + (size_t)gr * FIN + k0 + akk + 4);
    }
    float4 b0 = *(const float4*)(W1 + (size_t)(k0 + brow) * F1 + bc);
    float4 b1 = *(const float4*)(W1 + (size_t)(k0 + brow) * F1 + bc + 4);
    __syncthreads();
    Alds[(akk + 0) * 132 + arow] = a0.x;
    Alds[(akk + 1) * 132 + arow] = a0.y;
    Alds[(akk + 2) * 132 + arow] = a0.z;
    Alds[(akk + 3) * 132 + arow] = a0.w;
    Alds[(akk + 4) * 132 + arow] = a1.x;
    Alds[(akk + 5) * 132 + arow] = a1.y;
    Alds[(akk + 6) * 132 + arow] = a1.z;
    Alds[(akk + 7) * 132 + arow] = a1.w;
    *(float4*)(Blds + brow * 128 + bc) = b0;
    *(float4*)(Blds + brow * 128 + bc + 4) = b1;
    __syncthreads();
#pragma unroll
    for (int k = 0; k < 16; ++k) {
      float4 av0 = *(const float4*)(Alds + k * 132 + ty * 8);
      float4 av1 = *(const float4*)(Alds + k * 132 + ty * 8 + 4);
      float4 bv0 = *(const float4*)(Blds + k * 128 + tx * 8);
      float4 bv1 = *(const float4*)(Blds + k * 128 + tx * 8 + 4);
      float aa[8] = {av0.x, av0.y, av0.z, av0.w, av1.x, av1.y, av1.z, av1.w};
      float bb[8] = {bv0.x, bv0.y, bv0.z, bv0.w, bv1.x, bv1.y, bv1.z, bv1.w};
#pragma unroll
      for (int i = 0; i < 8; ++i)
#pragma unroll
        for (int j = 0; j < 8; ++j) acc[i][j] = fmaf(aa[i], bb[j], acc[i][j]);
    }
  }
#pragma unroll
  for (int i = 0; i < 8; ++i) {
    int gr = m0 + ty * 8 + i;
    if (gr < NN) {
      uint4 w;
      w.x = f2bf(acc[i][0]) | (f2bf(acc[i][1]) << 16);
      w.y = f2bf(acc[i][2]) | (f2bf(acc[i][3]) << 16);
      w.z = f2bf(acc[i][4]) | (f2bf(acc[i][5]) << 16);
      w.w = f2bf(acc[i][6]) | (f2bf(acc[i][7]) << 16);
      // SoA-by-phase: phase = tx>>2, offset within 16-u32 phase row = (tx&3)*4
      *(uint4*)(h1bf + ((size_t)(tx >> 2) * NN + gr) * 16 + (tx & 3) * 4) = w;
    }
  }
#pragma unroll
  for (int i = 0; i < 8; ++i) {
    float ps = 0.f, pd = 0.f;
#pragma unroll
    for (int j = 0; j < 8; ++j) {
      int c = tx * 8 + j;
      ps += acc[i][j] * att_s[c];
      pd += acc[i][j] * att_d[c];
    }
    ps += __shfl_xor(ps, 1); pd += __shfl_xor(pd, 1);
    ps += __shfl_xor(ps, 2); pd += __shfl_xor(pd, 2);
    if ((tx & 3) == 0) {
      int gr = m0 + ty * 8 + i;
      if (gr < NN) {
        int head = tx >> 2;
        a_src[gr * 4 + head] = ps;
        a_dst[gr * 4 + head] = pd;
      }
    }
  }
}

// ---- gather layer1: 16 lanes/node = 4 edge-groups x 4 column-lanes ----
// Edge-parallel: group g walks edges i = g, g+4, ... (scalar csr loads coalesce
// across groups). Serial dependent-load chain per lane: deg/4 instead of deg.
// Combine partial acc/ssum via shfl_xor(4|8). Phase->XCD affinity kept:
// d&7 -> xcd, p = xcd>>1, nb = (d>>3)*2 + (xcd&1).
__global__ __launch_bounds__(256) void gather1_kernel(const int* __restrict__ cnt,
                                                      const int* __restrict__ csr,
                                                      const float* __restrict__ a_src,
                                                      const float* __restrict__ a_dst,
                                                      const u32* __restrict__ h1bf,
                                                      const float* __restrict__ b1,
                                                      float* __restrict__ h1b,
                                                      float* __restrict__ bnsum,
                                                      float* __restrict__ bnsq) {
  __shared__ float bns[32], bnq[32];
  int t = threadIdx.x;
  if (t < 32) { bns[t] = 0.f; bnq[t] = 0.f; }
  __syncthreads();
  int d = blockIdx.x;
  int xcd = d & 7;
  int p = xcd >> 1;                     // head / column phase, pinned to XCD pair
  int nb = ((d >> 3) << 1) + (xcd & 1); // 0..3125
  int n = nb * 16 + (t >> 4);
  int sub = t & 15;
  int g = sub >> 2;                     // edge group 0..3
  int l = sub & 3;                      // column lane 0..3
  int f0 = p * 32 + l * 8;
  float acc[8] = {0.f, 0.f, 0.f, 0.f, 0.f, 0.f, 0.f, 0.f};
  float ssum = 0.f;
  if (n < NN) {
    float adst = a_dst[n * 4 + p];
    const u32* hb = h1bf + (size_t)p * NN * 16 + l * 4;   // SoA phase table
    if (g == 0) {
      // analytic self-loop: own row, coalesced across the block
      float e0 = a_src[n * 4 + p] + adst;
      e0 = e0 > 0.f ? e0 : 0.2f * e0;
      float x0 = __expf(e0);
      uint4 q = *(const uint4*)(hb + (size_t)n * 16);
      acc[0] = fmaf(x0, BF_LO(q.x), acc[0]); acc[1] = fmaf(x0, BF_HI(q.x), acc[1]);
      acc[2] = fmaf(x0, BF_LO(q.y), acc[2]); acc[3] = fmaf(x0, BF_HI(q.y), acc[3]);
      acc[4] = fmaf(x0, BF_LO(q.z), acc[4]); acc[5] = fmaf(x0, BF_HI(q.z), acc[5]);
      acc[6] = fmaf(x0, BF_LO(q.w), acc[6]); acc[7] = fmaf(x0, BF_HI(q.w), acc[7]);
      ssum += x0;
    }
    const int* row = csr + n * CAP;
    int m = cnt[n]; if (m > CAP) m = CAP;
    int i = g;
    for (; i + 4 < m; i += 8) {          // 2 independent gathers in flight
      int s0 = row[i];
      int s1 = row[i + 4];
      float e0 = a_src[s0 * 4 + p] + adst;
      float e1 = a_src[s1 * 4 + p] + adst;
      uint4 q0 = *(const uint4*)(hb + (size_t)s0 * 16);
      uint4 q1 = *(const uint4*)(hb + (size_t)s1 * 16);
      e0 = e0 > 0.f ? e0 : 0.2f * e0;  float x0 = __expf(e0);
      e1 = e1 > 0.f ? e1 : 0.2f * e1;  float x1 = __expf(e1);
      acc[0] = fmaf(x0, BF_LO(q0.x), acc[0]); acc[1] = fmaf(x0, BF_HI(q0.x), acc[1]);
      acc[2] = fmaf(x0, BF_LO(q0.y), acc[2]); acc[3] = fmaf(x0, BF_HI(q0.y), acc[3]);
      acc[4] = fmaf(x0, BF_LO(q0.z), acc[4]); acc[5] = fmaf(x0, BF_HI(q0.z), acc[5]);
      acc[6] = fmaf(x0, BF_LO(q0.w), acc[6]); acc[7] = fmaf(x0, BF_HI(q0.w), acc[7]);
      acc[0] = fmaf(x1, BF_LO(q1.x), acc[0]); acc[1] = fmaf(x1, BF_HI(q1.x), acc[1]);
      acc[2] = fmaf(x1, BF_LO(q1.y), acc[2]); acc[3] = fmaf(x1, BF_HI(q1.y), acc[3]);
      acc[4] = fmaf(x1, BF_LO(q1.z), acc[4]); acc[5] = fmaf(x1, BF_HI(q1.z), acc[5]);
      acc[6] = fmaf(x1, BF_LO(q1.w), acc[6]); acc[7] = fmaf(x1, BF_HI(q1.w), acc[7]);
      ssum += x0 + x1;
    }
    for (; i < m; i += 4) {
      int s0 = row[i];
      float e0 = a_src[s0 * 4 + p] + adst;
      e0 = e0 > 0.f ? e0 : 0.2f * e0;
      float x0 = __expf(e0);
      uint4 q = *(const uint4*)(hb + (size_t)s0 * 16);
      acc[0] = fmaf(x0, BF_LO(q.x), acc[0]); acc[1] = fmaf(x0, BF_HI(q.x), acc[1]);
      acc[2] = fmaf(x0, BF_LO(q.y), acc[2]); acc[3] = fmaf(x0, BF_HI(q.y), acc[3]);
      acc[4] = fmaf(x0, BF_LO(q.z), acc[4]); acc[5] = fmaf(x0, BF_HI(q.z), acc[5]);
      acc[6] = fmaf(x0, BF_LO(q.w), acc[6]); acc[7] = fmaf(x0, BF_HI(q.w), acc[7]);
      ssum += x0;
    }
  }
  // combine edge groups (bits 2,3 of lane id); node id (t>>4) unchanged by xor
#pragma unroll
  for (int j = 0; j < 8; ++j) {
    acc[j] += __shfl_xor(acc[j], 4);
    acc[j] += __shfl_xor(acc[j], 8);
  }
  ssum += __shfl_xor(ssum, 4);
  ssum += __shfl_xor(ssum, 8);
  if (n < NN && g == 0) {
    float inv = 1.f / (ssum + 1e-16f);
    float4 b0 = *(const float4*)(b1 + f0);
    float4 b4 = *(const float4*)(b1 + f0 + 4);
    float o[8];
    o[0] = acc[0] * inv + b0.x; o[1] = acc[1] * inv + b0.y;
    o[2] = acc[2] * inv + b0.z; o[3] = acc[3] * inv + b0.w;
    o[4] = acc[4] * inv + b4.x; o[5] = acc[5] * inv + b4.y;
    o[6] = acc[6] * inv + b4.z; o[7] = acc[7] * inv + b4.w;
    float4 w0 = {o[0], o[1], o[2], o[3]};
    float4 w1 = {o[4], o[5], o[6], o[7]};
    *(float4*)(h1b + (size_t)n * F1 + f0) = w0;
    *(float4*)(h1b + (size_t)n * F1 + f0 + 4) = w1;
    int lb = l * 8;
#pragma unroll
    for (int j = 0; j < 8; ++j) {
      atomicAdd(&bns[lb + j], o[j]);
      atomicAdd(&bnq[lb + j], o[j] * o[j]);
    }
  }
  __syncthreads();
  if (t < 32) {
    atomicAdd(bnsum + p * 32 + t, bns[t]);
    atomicAdd(bnsq + p * 32 + t, bnq[t]);
  }
}

// -- GEMM2 (BN stats + BN+ELU fused, a2 dots fused): h2 split A[64B]/B[16B] --
__global__ __launch_bounds__(256) void gemm2_kernel(const float* __restrict__ hpre,
                                                    const float* __restrict__ W2,
                                                    const float* __restrict__ bnsum,
                                                    const float* __restrict__ bnsq,
                                                    const float* __restrict__ gamma,
                                                    const float* __restrict__ beta,
                                                    u16* __restrict__ h2a,
                                                    u16* __restrict__ h2b,
                                                    const float* __restrict__ att_src2,
                                                    const float* __restrict__ att_dst2,
                                                    float* __restrict__ a_src2,
                                                    float* __restrict__ a_dst2) {
  __shared__ float Wlds[128 * 40];
  __shared__ float Alds[16 * 128];
  __shared__ float sc[128], sh[128];
  int t = threadIdx.x;
  for (int i = t; i < 128 * 40; i += 256) Wlds[i] = W2[i];
  if (t < 128) {
    const float invN = 1.f / (float)NN;
    float mu = bnsum[t] * invN;
    float var = bnsq[t] * invN - mu * mu;
    float s = gamma[t] * rsqrtf(var + 1e-5f);
    sc[t] = s;
    sh[t] = beta[t] - mu * s;
  }
  int tr = t >> 3;
  int tc = t & 7;
  float as5[5], ad5[5];
#pragma unroll
  for (int j = 0; j < 5; ++j) { as5[j] = att_src2[tc * 5 + j]; ad5[j] = att_dst2[tc * 5 + j]; }
  int n0 = blockIdx.x * 128;
  int lrow = t >> 1;
  int lkk = (t & 1) * 8;
  float acc[4][5];
#pragma unroll
  for (int i = 0; i < 4; ++i)
#pragma unroll
    for (int j = 0; j < 5; ++j) acc[i][j] = 0.f;

  for (int k0 = 0; k0 < F1; k0 += 16) {
    float av[8];
    int gn = n0 + lrow;
    if (gn < NN) {
      float4 v0 = *(const float4*)(hpre + (size_t)gn * F1 + k0 + lkk);
      float4 v1 = *(const float4*)(hpre + (size_t)gn * F1 + k0 + lkk + 4);
      av[0] = v0.x; av[1] = v0.y; av[2] = v0.z; av[3] = v0.w;
      av[4] = v1.x; av[5] = v1.y; av[6] = v1.z; av[7] = v1.w;
    } else {
#pragma unroll
      for (int j = 0; j < 8; ++j) av[j] = 0.f;
    }
    __syncthreads();
#pragma unroll
    for (int j = 0; j < 8; ++j) {
      int kg = k0 + lkk + j;
      float a = av[j] * sc[kg] + sh[kg];
      a = a > 0.f ? a : (__expf(a) - 1.f);
      Alds[(lkk + j) * 128 + lrow] = a;
    }
    __syncthreads();
#pragma unroll
    for (int k = 0; k < 16; ++k) {
      float4 a4 = *(const float4*)(Alds + k * 128 + tr * 4);
      float aa[4] = {a4.x, a4.y, a4.z, a4.w};
      float w[5];
#pragma unroll
      for (int j = 0; j < 5; ++j) w[j] = Wlds[(k0 + k) * 40 + tc * 5 + j];
#pragma unroll
      for (int i = 0; i < 4; ++i)
#pragma unroll
        for (int j = 0; j < 5; ++j) acc[i][j] = fmaf(aa[i], w[j], acc[i][j]);
    }
  }
#pragma unroll
  for (int i = 0; i < 4; ++i) {
    int gn = n0 + tr * 4 + i;
    if (gn < NN) {
#pragma unroll
      for (int j = 0; j < 5; ++j) {
        int f = tc * 5 + j;
        u16 v = (u16)f2bf(acc[i][j]);
        if (f < 32) h2a[(size_t)gn * 32 + f] = v;
        else        h2b[(size_t)gn * 8 + (f - 32)] = v;
      }
    }
  }
#pragma unroll
  for (int i = 0; i < 4; ++i) {
    float ps = 0.f, pd = 0.f;
#pragma unroll
    for (int j = 0; j < 5; ++j) { ps += acc[i][j] * as5[j]; pd += acc[i][j] * ad5[j]; }
#pragma unroll
    for (int off = 1; off < 8; off <<= 1) {
      ps += __shfl_xor(ps, off);
      pd += __shfl_xor(pd, off);
    }
    if (tc == 0) {
      int gn = n0 + tr * 4 + i;
      if (gn < NN) { a_src2[gn] = ps; a_dst2[gn] = pd; }
    }
  }
}

// ---- gather layer2: 16 lanes/node = 2 edge-groups x 8 feature-lanes ----
// l=0..3 load A (64B row), l=4 loads B, l=5..7 compute ssum only.
// Group g walks int4 chunks c = 4g, 4g+8, ...; combine via shfl_xor(8).
__global__ __launch_bounds__(256) void gather2_kernel(const int* __restrict__ cnt,
                                                      const int* __restrict__ csr,
                                                      const float* __restrict__ a_src,
                                                      const float* __restrict__ a_dst,
                                                      const u32* __restrict__ h2a,
                                                      const u32* __restrict__ h2b,
                                                      const float* __restrict__ b2,
                                                      float* __restrict__ out) {
  int t = threadIdx.x;
  int n = blockIdx.x * 16 + (t >> 4);
  if (n >= NN) return;
  int l = t & 7;
  int g = (t >> 3) & 1;
  bool act = (l < 5);
  bool isA = (l < 4);
  float adst = a_dst[n];
  float acc[8] = {0.f, 0.f, 0.f, 0.f, 0.f, 0.f, 0.f, 0.f};
  float ssum = 0.f;
  const uint4 zz = {0u, 0u, 0u, 0u};
  if (g == 0) {
    // analytic self-loop (own row, coalesced)
    float e0 = a_src[n] + adst;
    e0 = e0 > 0.f ? e0 : 0.2f * e0;
    float x0 = __expf(e0);
    uint4 q = act ? (isA ? *(const uint4*)(h2a + (size_t)n * 16 + l * 4)
                         : *(const uint4*)(h2b + (size_t)n * 4)) : zz;
    acc[0] = fmaf(x0, BF_LO(q.x), acc[0]); acc[1] = fmaf(x0, BF_HI(q.x), acc[1]);
    acc[2] = fmaf(x0, BF_LO(q.y), acc[2]); acc[3] = fmaf(x0, BF_HI(q.y), acc[3]);
    acc[4] = fmaf(x0, BF_LO(q.z), acc[4]); acc[5] = fmaf(x0, BF_HI(q.z), acc[5]);
    acc[6] = fmaf(x0, BF_LO(q.w), acc[6]); acc[7] = fmaf(x0, BF_HI(q.w), acc[7]);
    ssum += x0;
  }
  const int* row = csr + n * CAP;
  int m = cnt[n]; if (m > CAP) m = CAP;
  for (int c = 4 * g; c < m; c += 8) {
    if (c + 4 <= m) {
      int4 s4 = *(const int4*)(row + c);
      float e0 = a_src[s4.x] + adst;
      float e1 = a_src[s4.y] + adst;
      float e2 = a_src[s4.z] + adst;
      float e3 = a_src[s4.w] + adst;
      uint4 q0 = act ? (isA ? *(const uint4*)(h2a + (size_t)s4.x * 16 + l * 4)
                            : *(const uint4*)(h2b + (size_t)s4.x * 4)) : zz;
      uint4 q1 = act ? (isA ? *(const uint4*)(h2a + (size_t)s4.y * 16 + l * 4)
                            : *(const uint4*)(h2b + (size_t)s4.y * 4)) : zz;
      uint4 q2 = act ? (isA ? *(const uint4*)(h2a + (size_t)s4.z * 16 + l * 4)
                            : *(const uint4*)(h2b + (size_t)s4.z * 4)) : zz;
      uint4 q3 = act ? (isA ? *(const uint4*)(h2a + (size_t)s4.w * 16 + l * 4)
                            : *(const uint4*)(h2b + (size_t)s4.w * 4)) : zz;
      e0 = e0 > 0.f ? e0 : 0.2f * e0;  float x0 = __expf(e0);
      e1 = e1 > 0.f ? e1 : 0.2f * e1;  float x1 = __expf(e1);
      e2 = e2 > 0.f ? e2 : 0.2f * e2;  float x2 = __expf(e2);
      e3 = e3 > 0.f ? e3 : 0.2f * e3;  float x3 = __expf(e3);
      acc[0] = fmaf(x0, BF_LO(q0.x), acc[0]); acc[1] = fmaf(x0, BF_HI(q0.x), acc[1]);
      acc[2] = fmaf(x0, BF_LO(q0.y), acc[2]); acc[3] = fmaf(x0, BF_HI(q0.y), acc[3]);
      acc[4] = fmaf(x0, BF_LO(q0.z), acc[4]); acc[5] = fmaf(x0, BF_HI(q0.z), acc[5]);
      acc[6] = fmaf(x0, BF_LO(q0.w), acc[6]); acc[7] = fmaf(x0, BF_HI(q0.w), acc[7]);
      acc[0] = fmaf(x1, BF_LO(q1.x), acc[0]); acc[1] = fmaf(x1, BF_HI(q1.x), acc[1]);
      acc[2] = fmaf(x1, BF_LO(q1.y), acc[2]); acc[3] = fmaf(x1, BF_HI(q1.y), acc[3]);
      acc[4] = fmaf(x1, BF_LO(q1.z), acc[4]); acc[5] = fmaf(x1, BF_HI(q1.z), acc[5]);
      acc[6] = fmaf(x1, BF_LO(q1.w), acc[6]); acc[7] = fmaf(x1, BF_HI(q1.w), acc[7]);
      acc[0] = fmaf(x2, BF_LO(q2.x), acc[0]); acc[1] = fmaf(x2, BF_HI(q2.x), acc[1]);
      acc[2] = fmaf(x2, BF_LO(q2.y), acc[2]); acc[3] = fmaf(x2, BF_HI(q2.y), acc[3]);
      acc[4] = fmaf(x2, BF_LO(q2.z), acc[4]); acc[5] = fmaf(x2, BF_HI(q2.z), acc[5]);
      acc[6] = fmaf(x2, BF_LO(q2.w), acc[6]); acc[7] = fmaf(x2, BF_HI(q2.w), acc[7]);
      acc[0] = fmaf(x3, BF_LO(q3.x), acc[0]); acc[1] = fmaf(x3, BF_HI(q3.x), acc[1]);
      acc[2] = fmaf(x3, BF_LO(q3.y), acc[2]); acc[3] = fmaf(x3, BF_HI(q3.y), acc[3]);
      acc[4] = fmaf(x3, BF_LO(q3.z), acc[4]); acc[5] = fmaf(x3, BF_HI(q3.z), acc[5]);
      acc[6] = fmaf(x3, BF_LO(q3.w), acc[6]); acc[7] = fmaf(x3, BF_HI(q3.w), acc[7]);
      ssum += x0 + x1 + x2 + x3;
    } else {
      for (int i = c; i < m; ++i) {
        int s0 = row[i];
        float e0 = a_src[s0] + adst;
        e0 = e0 > 0.f ? e0 : 0.2f * e0;
        float x0 = __expf(e0);
        uint4 q = act ? (isA ? *(const uint4*)(h2a + (size_t)s0 * 16 + l * 4)
                             : *(const uint4*)(h2b + (size_t)s0 * 4)) : zz;
        acc[0] = fmaf(x0, BF_LO(q.x), acc[0]); acc[1] = fmaf(x0, BF_HI(q.x), acc[1]);
        acc[2] = fmaf(x0, BF_LO(q.y), acc[2]); acc[3] = fmaf(x0, BF_HI(q.y), acc[3]);
        acc[4] = fmaf(x0, BF_LO(q.z), acc[4]); acc[5] = fmaf(x0, BF_HI(q.z), acc[5]);
        acc[6] = fmaf(x0, BF_LO(q.w), acc[6]); acc[7] = fmaf(x0, BF_HI(q.w), acc[7]);
        ssum += x0;
      }
    }
  }
  // combine the two edge groups (bit 3 of lane id; node id t>>4 unchanged)
#pragma unroll
  for (int j = 0; j < 8; ++j) acc[j] += __shfl_xor(acc[j], 8);
  ssum += __shfl_xor(ssum, 8);
  float inv = 1.f / (ssum + 1e-16f);
  if (g == 0 && act) {
    float* op = out + (size_t)n * F2 + l * 8;
#pragma unroll
    for (int j = 0; j < 8; ++j) op[j] = acc[j] * inv + b2[l * 8 + j];
  }
}

extern "C" void kernel_launch(void* const* d_in, const int* in_sizes, int n_in,
                              void* d_out, int out_size, void* d_ws, size_t ws_size,
                              hipStream_t stream) {
  const float* x        = (const float*)d_in[0];
  const int*   ei       = (const int*)d_in[1];
  const float* W1       = (const float*)d_in[2];
  const float* att_src1 = (const float*)d_in[3];
  const float* att_dst1 = (const float*)d_in[4];
  const float* b1       = (const float*)d_in[5];
  const float* gamma    = (const float*)d_in[6];
  const float* beta     = (const float*)d_in[7];
  const float* W2       = (const float*)d_in[8];
  const float* att_src2 = (const float*)d_in[9];
  const float* att_dst2 = (const float*)d_in[10];
  const float* b2       = (const float*)d_in[11];
  float* out = (float*)d_out;

  // ---- workspace layout (16B-aligned chunks) ----
  int* cnt      = (int*)d_ws;                  // 50048 (zeroed)
  float* bnsum  = (float*)(cnt + 50048);       // 128   (zeroed)
  float* bnsq   = bnsum + 128;                 // 128   (zeroed)
  int* csr      = (int*)(bnsq + 128);          // 50000*48 = 2,400,000
  u32* h1bf     = (u32*)(csr + NN * CAP);      // 3,200,000 (4 phases * 50000*16)
  float* h1b    = (float*)(h1bf + 3200000);    // 6,400,000
  u32* h2a      = (u32*)(h1b + 6400000);       // 800,000 (50000*16, 64B rows)
  u32* h2b      = h2a + 800000;                // 200,000 (50000*4, 16B rows)
  float* a_src1 = (float*)(h2b + 200000);      // 200000
  float* a_dst1 = a_src1 + 200000;             // 200000
  float* a_src2 = a_dst1 + 200000;             // 50000
  float* a_dst2 = a_src2 + 50000;              // 50000

  hipMemsetAsync(cnt, 0, (50048 + 256) * sizeof(int), stream);

  g1f_kernel<<<G1B + FILLB, 256, 0, stream>>>(x, W1, att_src1, att_dst1,
                                              h1bf, a_src1, a_dst1,
                                              ei, cnt, csr);
  gather1_kernel<<<(G1PB / 2) * 8, 256, 0, stream>>>(cnt, csr, a_src1, a_dst1,
                                                     h1bf, b1, h1b, bnsum, bnsq);
  gemm2_kernel<<<(NN + 127) / 128, 256, 0, stream>>>(h1b, W2, bnsum, bnsq,
                                                     gamma, beta,
                                                     (u16*)h2a, (u16*)h2b,
                                                     att_src2, att_dst2,
                                                     a_src2, a_dst2);
  gather2_kernel<<<G2B, 256, 0, stream>>>(cnt, csr, a_src2, a_dst2,
                                          h2a, h2b, b2, out);
}